// Round 8
// baseline (246.815 us; speedup 1.0000x reference)
//
#include <hip/hip_runtime.h>
#include <hip/hip_bf16.h>

#define T_DIM 1024
#define B_DIM 4
#define E_DIM 1024
#define H_DIM 16
#define HD    64
#define M_DIM (T_DIM * B_DIM)   // 4096

typedef __hip_bfloat16 bf16;
typedef __bf16 bf16x8 __attribute__((ext_vector_type(8)));
typedef __bf16 bf16x4 __attribute__((ext_vector_type(4)));
typedef __bf16 bf16x2 __attribute__((ext_vector_type(2)));
typedef float  f32x4  __attribute__((ext_vector_type(4)));

#define P4S ((size_t)M_DIM * E_DIM)   // 4194304
#define P1S ((size_t)E_DIM * E_DIM)   // 1048576

// ------------------------------------------- fused f32 -> bf16 (all 8 buffers)
__global__ __launch_bounds__(256) void cvt_all(
    const float* __restrict__ q, const float* __restrict__ k,
    const float* __restrict__ v, const float* __restrict__ w0,
    const float* __restrict__ w1, const float* __restrict__ w2,
    const float* __restrict__ w3, const float* __restrict__ w4,
    __bf16* __restrict__ dst)
{
  size_t i = ((size_t)blockIdx.x * 256 + threadIdx.x) * 8;
  const float* src;
  size_t off;
  if (i < P4S)            { src = q; off = i; }
  else if (i < 2 * P4S)   { src = k; off = i - P4S; }
  else if (i < 3 * P4S)   { src = v; off = i - 2 * P4S; }
  else {
    size_t j = i - 3 * P4S;
    int wsel = (int)(j >> 20);          // /P1S
    off = j & (P1S - 1);
    const float* ws[5] = {w0, w1, w2, w3, w4};
    src = ws[wsel];
  }
  float4 a = *(const float4*)(src + off);
  float4 b = *(const float4*)(src + off + 4);
  bf16x8 o;
  o[0] = (__bf16)a.x; o[1] = (__bf16)a.y; o[2] = (__bf16)a.z; o[3] = (__bf16)a.w;
  o[4] = (__bf16)b.x; o[5] = (__bf16)b.y; o[6] = (__bf16)b.z; o[7] = (__bf16)b.w;
  *(bf16x8*)(dst + i) = o;
}

// ------------------------------------------------- async global->LDS, 16 B/lane
__device__ __forceinline__ void load_lds16(const __bf16* g, __bf16* l) {
  __builtin_amdgcn_global_load_lds(
      (__attribute__((address_space(1))) void*)(void*)g,
      (__attribute__((address_space(3))) void*)l, 16, 0, 0);
}

// =======================================================================
// 256x256 8-phase GEMM (BK=64, 8 waves, dbuf LDS, counted vmcnt, swizzle)
// + fused norm epilogue: z=0 -> qn[bh][t], z=1/2 -> knr[bh][kt32][which][32]
// =======================================================================
__device__ __forceinline__ void stage_half(
    int H, const __bf16* __restrict__ X, const __bf16* __restrict__ W,
    int bm, int bn, __bf16* As, __bf16* Bs, int tid)
{
  if (H >= 64) return;                 // K=1024 -> 16 tiles -> 64 half-tiles
  const int T  = H >> 2;
  const int h  = H & 3;
  const int rh = (h & 1) * 128;
  const __bf16* src = (h < 2) ? X : W;
  const int rbase   = (h < 2) ? bm : bn;
  __bf16* lb = ((h < 2) ? As : Bs) + (T & 1) * 16384;
#pragma unroll
  for (int li = 0; li < 2; ++li) {
    int r  = rh + li * 64 + (tid >> 3);          // row within 256-row tile
    int gc = (tid & 7) ^ (r & 7);                // pre-swizzled source chunk
    load_lds16(src + (size_t)(rbase + r) * E_DIM + T * 64 + gc * 8,
               lb + (rh + li * 64) * 64 + tid * 8);   // linear dest
  }
}

#define RD(base, row, c) \
  (*(const bf16x8*)((base) + (row) * 64 + ((((c) ^ ((row) & 7))) << 3)))

__global__ __launch_bounds__(512, 2) void proj_gemm4(
    const __bf16* __restrict__ xbase, const __bf16* __restrict__ wbase,
    const float* __restrict__ bin, __bf16* __restrict__ cbase,
    float* __restrict__ qn_g, float* __restrict__ knr_g)
{
  __shared__ __bf16 lds[65536];        // 128 KiB
  __bf16* As = lds;
  __bf16* Bs = lds + 32768;

  const int z = blockIdx.z;
  const __bf16* X = xbase + ((z == 0) ? 0 : (z == 3) ? 2 * P4S : P4S);
  const __bf16* W = wbase + (size_t)z * P1S;
  const float* bias = bin + z * E_DIM;
  __bf16* C = cbase + (size_t)z * P4S;

  const int bm = blockIdx.x * 256;
  const int bn = blockIdx.y * 256;

  const int tid  = threadIdx.x;
  const int lane = tid & 63;
  const int w    = tid >> 6;           // 8 waves
  const int wm   = w >> 2;
  const int wn   = w & 3;
  const int mrow = lane & 15, quad = lane >> 4;

  f32x4 acc[8][4];
#pragma unroll
  for (int m = 0; m < 8; ++m)
#pragma unroll
    for (int n = 0; n < 4; ++n) acc[m][n] = (f32x4)0.0f;

#pragma unroll
  for (int H = 0; H < 5; ++H) stage_half(H, X, W, bm, bn, As, Bs, tid);
  asm volatile("s_waitcnt vmcnt(2)" ::: "memory");
  __builtin_amdgcn_s_barrier();

  bf16x8 af[4][2];
  bf16x8 bq[4][2];

#pragma unroll 2
  for (int t = 0; t < 16; ++t) {
    const __bf16* Ab = As + (t & 1) * 16384;
    const __bf16* Bb = Bs + (t & 1) * 16384;

    // phase 0
#pragma unroll
    for (int n = 0; n < 2; ++n)
#pragma unroll
      for (int kk = 0; kk < 2; ++kk)
        bq[n][kk] = RD(Bb, wn * 64 + n * 16 + mrow, kk * 4 + quad);
#pragma unroll
    for (int m = 0; m < 4; ++m)
#pragma unroll
      for (int kk = 0; kk < 2; ++kk)
        af[m][kk] = RD(Ab, wm * 128 + m * 16 + mrow, kk * 4 + quad);
    stage_half(4 * t + 5, X, W, bm, bn, As, Bs, tid);
    __builtin_amdgcn_s_barrier();
    asm volatile("s_waitcnt lgkmcnt(0)" ::: "memory");
    __builtin_amdgcn_s_setprio(1);
#pragma unroll
    for (int kk = 0; kk < 2; ++kk)
#pragma unroll
      for (int n = 0; n < 2; ++n)
#pragma unroll
        for (int m = 0; m < 4; ++m)
          acc[m][n] = __builtin_amdgcn_mfma_f32_16x16x32_bf16(
              af[m][kk], bq[n][kk], acc[m][n], 0, 0, 0);
    __builtin_amdgcn_s_setprio(0);
    __builtin_amdgcn_s_barrier();

    // phase 1
#pragma unroll
    for (int n = 2; n < 4; ++n)
#pragma unroll
      for (int kk = 0; kk < 2; ++kk)
        bq[n][kk] = RD(Bb, wn * 64 + n * 16 + mrow, kk * 4 + quad);
    stage_half(4 * t + 6, X, W, bm, bn, As, Bs, tid);
    __builtin_amdgcn_s_barrier();
    asm volatile("s_waitcnt lgkmcnt(0)" ::: "memory");
    __builtin_amdgcn_s_setprio(1);
#pragma unroll
    for (int kk = 0; kk < 2; ++kk)
#pragma unroll
      for (int n = 2; n < 4; ++n)
#pragma unroll
        for (int m = 0; m < 4; ++m)
          acc[m][n] = __builtin_amdgcn_mfma_f32_16x16x32_bf16(
              af[m][kk], bq[n][kk], acc[m][n], 0, 0, 0);
    __builtin_amdgcn_s_setprio(0);
    __builtin_amdgcn_s_barrier();

    // phase 2
#pragma unroll
    for (int m = 0; m < 4; ++m)
#pragma unroll
      for (int kk = 0; kk < 2; ++kk)
        af[m][kk] = RD(Ab, wm * 128 + 64 + m * 16 + mrow, kk * 4 + quad);
    stage_half(4 * t + 7, X, W, bm, bn, As, Bs, tid);
    __builtin_amdgcn_s_barrier();
    asm volatile("s_waitcnt lgkmcnt(0)" ::: "memory");
    __builtin_amdgcn_s_setprio(1);
#pragma unroll
    for (int kk = 0; kk < 2; ++kk)
#pragma unroll
      for (int n = 0; n < 2; ++n)
#pragma unroll
        for (int m = 0; m < 4; ++m)
          acc[4 + m][n] = __builtin_amdgcn_mfma_f32_16x16x32_bf16(
              af[m][kk], bq[n][kk], acc[4 + m][n], 0, 0, 0);
    __builtin_amdgcn_s_setprio(0);
    __builtin_amdgcn_s_barrier();

    // phase 3
    stage_half(4 * t + 8, X, W, bm, bn, As, Bs, tid);
    __builtin_amdgcn_s_barrier();
    __builtin_amdgcn_s_setprio(1);
#pragma unroll
    for (int kk = 0; kk < 2; ++kk)
#pragma unroll
      for (int n = 2; n < 4; ++n)
#pragma unroll
        for (int m = 0; m < 4; ++m)
          acc[4 + m][n] = __builtin_amdgcn_mfma_f32_16x16x32_bf16(
              af[m][kk], bq[n][kk], acc[4 + m][n], 0, 0, 0);
    __builtin_amdgcn_s_setprio(0);
    if (t < 14)       { asm volatile("s_waitcnt vmcnt(2)" ::: "memory"); }
    else if (t == 14) { asm volatile("s_waitcnt vmcnt(0)" ::: "memory"); }
    __builtin_amdgcn_s_barrier();
  }

  // epilogue: store C + accumulate row-norms of the bf16-rounded values
  f32x4 ns[8];
#pragma unroll
  for (int m = 0; m < 8; ++m) ns[m] = (f32x4)0.0f;
#pragma unroll
  for (int n = 0; n < 4; ++n) {
    int col = bn + wn * 64 + n * 16 + mrow;
    float bc = bias[col];
#pragma unroll
    for (int m = 0; m < 8; ++m) {
      int rbase = bm + wm * 128 + m * 16 + quad * 4;
#pragma unroll
      for (int r = 0; r < 4; ++r) {
        __bf16 xb = (__bf16)(acc[m][n][r] + bc);
        C[(size_t)(rbase + r) * E_DIM + col] = xb;
        float xv = (float)xb;
        ns[m][r] = fmaf(xv, xv, ns[m][r]);
      }
    }
  }
  if (z < 3) {
#pragma unroll
    for (int m = 0; m < 8; ++m)
#pragma unroll
      for (int d = 1; d < 16; d <<= 1) {
        f32x4 o;
#pragma unroll
        for (int r = 0; r < 4; ++r) o[r] = __shfl_xor(ns[m][r], d, 64);
        ns[m] += o;
      }
    if (mrow == 0) {
      int hh = (bn >> 6) + wn;           // head index of this wave's 64 cols
#pragma unroll
      for (int m = 0; m < 8; ++m) {
        int t = (bm >> 2) + wm * 32 + m * 4 + quad;   // token index (b = r)
#pragma unroll
        for (int r = 0; r < 4; ++r) {
          int bhh = r * 16 + hh;
          float v = ns[m][r];
          if (z == 0)
            qn_g[bhh * 1024 + t] = v;
          else
            knr_g[bhh * 2048 + (t >> 5) * 64 + ((z == 2) ? 32 : 0)
                  + (t & 15) * 2 + ((t >> 4) & 1)] = v;
        }
      }
    }
  }
}

// --------------------------------------------------- GEMM core (128x128, BK=32)
template <typename TO>
__device__ __forceinline__ void gemm_body(
    const __bf16* __restrict__ X, const __bf16* __restrict__ W,
    const float* __restrict__ bias, TO* __restrict__ C,
    int bm, int bn, int Ndim, int Kdim, __bf16* As, __bf16* Bs)
{
  const int tid  = threadIdx.x;
  const int lane = tid & 63;
  const int wave = tid >> 6;
  const int wy = (wave >> 1) * 64;
  const int wx = (wave & 1) * 64;
  const int mrow = lane & 15, quad = lane >> 4;

  const int srow = tid >> 2;
  const int ke   = (tid & 3) * 8;
  const __bf16* gA0 = X + (size_t)(bm + srow)      * Kdim + ke;
  const __bf16* gA1 = X + (size_t)(bm + srow + 64) * Kdim + ke;
  const __bf16* gB0 = W + (size_t)(bn + srow)      * Kdim + ke;
  const __bf16* gB1 = W + (size_t)(bn + srow + 64) * Kdim + ke;
  __bf16* lA0 = As + tid * 8;
  __bf16* lA1 = As + (tid + 256) * 8;
  __bf16* lB0 = Bs + tid * 8;
  __bf16* lB1 = Bs + (tid + 256) * 8;

  f32x4 acc[4][4];
#pragma unroll
  for (int i = 0; i < 4; ++i)
#pragma unroll
    for (int j = 0; j < 4; ++j) acc[i][j] = (f32x4)0.0f;

  for (int k0 = 0; k0 < Kdim; k0 += 32) {
    __syncthreads();
    load_lds16(gA0 + k0, lA0);
    load_lds16(gA1 + k0, lA1);
    load_lds16(gB0 + k0, lB0);
    load_lds16(gB1 + k0, lB1);
    __syncthreads();
    bf16x8 af[4], bf[4];
#pragma unroll
    for (int i = 0; i < 4; ++i)
      af[i] = *(const bf16x8*)(As + (wy + i * 16 + mrow) * 32 + quad * 8);
#pragma unroll
    for (int j = 0; j < 4; ++j)
      bf[j] = *(const bf16x8*)(Bs + (wx + j * 16 + mrow) * 32 + quad * 8);
#pragma unroll
    for (int i = 0; i < 4; ++i)
#pragma unroll
      for (int j = 0; j < 4; ++j)
        acc[i][j] = __builtin_amdgcn_mfma_f32_16x16x32_bf16(af[i], bf[j], acc[i][j], 0, 0, 0);
  }

#pragma unroll
  for (int j = 0; j < 4; ++j) {
    int col = bn + wx + j * 16 + mrow;
    float bc = bias[col];
#pragma unroll
    for (int i = 0; i < 4; ++i) {
      int rbase = bm + wy + i * 16 + quad * 4;
#pragma unroll
      for (int r = 0; r < 4; ++r)
        C[(size_t)(rbase + r) * Ndim + col] = (TO)(acc[i][j][r] + bc);
    }
  }
}

// Output projection (f32 out).
__global__ __launch_bounds__(256) void out_gemm(
    const __bf16* __restrict__ X, const __bf16* __restrict__ W,
    const float* __restrict__ bias, float* __restrict__ C)
{
  __shared__ __bf16 As[128 * 32];
  __shared__ __bf16 Bs[128 * 32];
  gemm_body<float>(X, W, bias, C, blockIdx.x * 128, blockIdx.y * 128,
                   E_DIM, E_DIM, As, Bs);
}

// ------------------------------------------ V transpose (norms in proj)
// Vt_g[bh][d][kt32*32 + s32(k)] = V[kt32*32+k][d], s32(k) = (k&15)*2 + (k>>4)
__global__ __launch_bounds__(256) void vt_only(
    const __bf16* __restrict__ Vp, __bf16* __restrict__ Vt_g)
{
  __shared__ __bf16 tile[64][88];
  const int tid = threadIdx.x;
  const int bh = blockIdx.x & 63, kt = blockIdx.x >> 6;   // kt = 64-key tile
  const int b = bh >> 4, h = bh & 15;
  {
    int s = tid >> 2, d0 = (tid & 3) * 16;
    const __bf16* src = Vp + (size_t)((kt * 64 + s) * 4 + b) * 1024 + h * 64 + d0;
    *(bf16x8*)(&tile[s][d0])     = *(const bf16x8*)(src);
    *(bf16x8*)(&tile[s][d0 + 8]) = *(const bf16x8*)(src + 8);
  }
  __syncthreads();
#pragma unroll
  for (int c = 0; c < 2; ++c) {
    int idx = tid * 2 + c;
    int d = idx >> 3, u0 = (idx & 7) * 8;
    bf16x8 o;
#pragma unroll
    for (int i = 0; i < 8; ++i) {
      int u = u0 + i;
      int s = (u >> 5) * 32 + ((u & 31) >> 1) + (u & 1) * 16;  // sigma32^-1
      o[i] = tile[s][d];
    }
    *(bf16x8*)(Vt_g + ((size_t)bh * 64 + d) * 1024 + kt * 64 + u0) = o;
  }
}

// -------------------------------------------------------- MFMA flash attention
// r6 structure with the CORRECT register cap + r7 conflict-free layouts:
// 512 thr / 8 waves = 2 key-groups x 4 waves, same 128 q-rows (32 q/wave,
// m-blocked). Group g owns keys [g*512, g*512+512) as 16 KVBLK=32 dbuf tiles.
// __launch_bounds__(512, 2): hipcc arg2 = min WORKGROUPS/CU (observed r4/r6:
// (512,4) -> 60-64 VGPR = 32-wave cap) => cap 16 waves/CU => 128 VGPR. 72 KB
// LDS -> 2 blocks/CU => 16 waves/CU (4/SIMD), 2x r7. Zero global ops in loop;
// counted vmcnt(3); in-LDS cross-group combine (validated r6).
__global__ __launch_bounds__(512, 2) void mgk_attn_mfma(
    const __bf16* __restrict__ Qp, const __bf16* __restrict__ K1p,
    const __bf16* __restrict__ K2p, const __bf16* __restrict__ Vt_g,
    const float* __restrict__ qn_g, const float* __restrict__ knr_g,
    const float* __restrict__ pi, __bf16* __restrict__ AO)
{
  // 4 bufs x 6144 {K1 2048|K2 2048|Vt 2048} | Pl 8x1024 | kn 2048 f32
  __shared__ __bf16 lds[36864];          // 72 KB -> 2 blocks/CU
  __bf16* Pl  = lds + 24576;             // 8 waves x 16 rows x 64 elems
  float*  knl = (float*)(lds + 32768);   // 2048 f32: [kt32 0..31][{k1,k2}x32]

  const int bid = blockIdx.x;
  const int bh  = (bid & 7) * 8 + ((bid >> 3) & 7);   // XCD-local bh groups
  const int qt  = bid >> 6;                           // 0..7
  const int b = bh >> 4, h = bh & 15;
  const int tid = threadIdx.x, lane = tid & 63, w = tid >> 6;   // 8 waves
  const int g = w >> 2, wg = w & 3;      // key-group, wave-in-group
  const int gtid = tid & 255;
  const int mrow = lane & 15, quad = lane >> 4;

  const float cl1 = 0.0625f * 1.4426950408889634f;   // (scaling/2)*log2e
  const float cl2 = 0.1875f * 1.4426950408889634f;   // (3*scaling/2)*log2e
  const float L1 = 2.0f * cl1, L2 = 2.0f * cl2;
  const float p1 = fminf(fmaxf(fabsf(pi[h]), 1e-6f), 2.0f);
  const float p2 = fminf(fmaxf(fabsf(pi[H_DIM + h]), 1e-6f), 2.0f);
  const float lp1 = __log2f(p1), lp2 = __log2f(p2);
  const int hoff = h * 64;

  // Q fragments (loop-invariant; same rows for both groups)
  bf16x8 af[2][2];
  f32x4 aq2[2];
#pragma unroll
  for (int m = 0; m < 2; ++m) {
    const __bf16* qp = Qp + (size_t)((qt * 128 + wg * 32 + m * 16 + mrow) * 4 + b) * 1024
                       + hoff + quad * 8;
    af[m][0] = *(const bf16x8*)(qp);
    af[m][1] = *(const bf16x8*)(qp + 32);
    f32x4 qnv = *(const f32x4*)(qn_g + bh * 1024 + qt * 128 + wg * 32 + m * 16 + quad * 4);
#pragma unroll
    for (int r = 0; r < 4; ++r) aq2[m][r] = fmaf(cl1 - cl2, qnv[r], lp2);
  }

  // staging geometry (per 256-thread group; r7 conflict-free layouts)
  const int srow = gtid >> 3;                      // 0..31
  const int pch  = gtid & 7;                       // physical chunk (linear dest)
  const int gcK  = pch ^ (srow & 7);               // K: logical d-chunk
  const __bf16* gK1 = K1p + (size_t)(srow * 4 + b) * 1024 + hoff + gcK * 8;
  const __bf16* gK2 = K2p + (size_t)(srow * 4 + b) * 1024 + hoff + gcK * 8;
  const int vcl = pch ^ (srow & 7);                // Vt: logical chunk
  const int vd  = (vcl >> 2) * 32 + srow;          // logical d row
  const int vu0 = (vcl & 3) * 8;                   // u start
  const __bf16* gVt = Vt_g + ((size_t)bh * 64 + vd) * 1024 + vu0;

  // group g tile i (i=0..15) -> 32-key tile index kt32 = g*16+i
#define STAGE_T(i_, bsel_) do {                                               \
    __bf16* bb_ = lds + (bsel_) * 6144;                                       \
    int kt_ = g * 16 + (i_);                                                  \
    load_lds16(gK1 + (size_t)kt_ * 131072, bb_ + gtid * 8);                   \
    load_lds16(gK2 + (size_t)kt_ * 131072, bb_ + 2048 + gtid * 8);            \
    load_lds16(gVt + kt_ * 32,             bb_ + 4096 + gtid * 8);            \
  } while (0)

  // prologue: kn (1 load/thread: 2048 f32 / 512 thr = 16 B) + tiles 0,1
  load_lds16((const __bf16*)(knr_g + bh * 2048 + tid * 4),
             (__bf16*)knl + tid * 8);
  STAGE_T(0, g * 2);
  STAGE_T(1, g * 2 + 1);
  asm volatile("s_waitcnt vmcnt(3)" ::: "memory");   // kn + own tile0 landed
  __builtin_amdgcn_s_barrier();

  f32x4 oacc[2][4];
#pragma unroll
  for (int m = 0; m < 2; ++m)
#pragma unroll
    for (int j = 0; j < 4; ++j) oacc[m][j] = (f32x4)0.0f;
  f32x4 rsl[2] = {(f32x4)0.0f, (f32x4)0.0f};

  for (int i = 0; i < 16; ++i) {
    const __bf16* buf = lds + (g * 2 + (i & 1)) * 6144;
    const __bf16* K1s = buf;
    const __bf16* K2s = buf + 2048;
    const __bf16* Vts = buf + 4096;

    // per-tile key-norm constants from LDS (zero global ops in loop)
    const float* knt = knl + (g * 16 + i) * 64;
    float2 f1 = *(const float2*)(knt + mrow * 2);
    float2 f2 = *(const float2*)(knt + 32 + mrow * 2);
    float nb1[2], s2v[2];
    nb1[0] = fmaf(-cl1, f1.x, lp1); nb1[1] = fmaf(-cl1, f1.y, lp1);
    s2v[0] = -cl2 * f2.x;           s2v[1] = -cl2 * f2.y;

    // ---- S1, S2 via MFMA (each K-frag read feeds both m-blocks) ----
    f32x4 acc1[2][2], acc2[2][2];
#pragma unroll
    for (int m = 0; m < 2; ++m)
#pragma unroll
      for (int j = 0; j < 2; ++j) { acc1[m][j] = (f32x4)0.0f; acc2[m][j] = (f32x4)0.0f; }
    __builtin_amdgcn_s_setprio(1);
#pragma unroll
    for (int kk = 0; kk < 2; ++kk)
#pragma unroll
      for (int j = 0; j < 2; ++j) {
        int row = j * 16 + mrow;
        int off = row * 64 + (((kk * 4 + quad) ^ (row & 7)) << 3);
        bf16x8 b1f = *(const bf16x8*)(K1s + off);
        bf16x8 b2f = *(const bf16x8*)(K2s + off);
#pragma unroll
        for (int m = 0; m < 2; ++m) {
          acc1[m][j] = __builtin_amdgcn_mfma_f32_16x16x32_bf16(af[m][kk], b1f, acc1[m][j], 0, 0, 0);
          acc2[m][j] = __builtin_amdgcn_mfma_f32_16x16x32_bf16(af[m][kk], b2f, acc2[m][j], 0, 0, 0);
        }
      }
    __builtin_amdgcn_s_setprio(0);

    // ---- P' = exp2(L1*S1 + nb1[j]) + exp2(L2*S2 + s2v[j] + aq2[m][r]) ----
#pragma unroll
    for (int m = 0; m < 2; ++m) {
      f32x4 pj[2];
#pragma unroll
      for (int j = 0; j < 2; ++j) {
        f32x4 p;
#pragma unroll
        for (int r = 0; r < 4; ++r) {
          float e1 = __builtin_amdgcn_exp2f(fmaf(L1, acc1[m][j][r], nb1[j]));
          float e2 = __builtin_amdgcn_exp2f(fmaf(L2, acc2[m][j][r], s2v[j] + aq2[m][r]));
          p[r] = e1 + e2;
        }
        pj[j] = p;
        rsl[m] += p;
      }
      // key j*16+mrow -> sigma32 slot u = mrow*2+j; paired-row swizzled write
#pragma unroll
      for (int r = 0; r < 4; ++r) {
        int row  = quad * 4 + r;                     // q & 15
        int phys = (m * 4 + (mrow >> 2)) ^ (row & 7);
        bf16x2 pk; pk[0] = (__bf16)pj[0][r]; pk[1] = (__bf16)pj[1][r];
        *(bf16x2*)(Pl + w * 1024 + row * 64 + phys * 8 + (mrow & 3) * 2) = pk;
      }
    }
    // Pl is wave-private; per-wave LDS ops are in-order -> no barrier.

    // ---- O += P * V (paired-row swizzled reads; each vf feeds 2 MFMAs) ----
    bf16x8 pf[2];
#pragma unroll
    for (int m = 0; m < 2; ++m)
      pf[m] = *(const bf16x8*)(Pl + w * 1024 + mrow * 64
                               + (((m * 4 + quad) ^ (mrow & 7)) << 3));
    __builtin_amdgcn_s_setprio(1);
#pragma unroll
    for (int j = 0; j < 4; ++j) {
      int rowv = (j & 1) * 16 + mrow;                // d & 31
      int cl   = (j >> 1) * 4 + quad;
      bf16x8 vf = *(const bf16x8*)(Vts + rowv * 64 + ((cl ^ (rowv & 7)) << 3));
#pragma unroll
      for (int m = 0; m < 2; ++m)
        oacc[m][j] = __builtin_amdgcn_mfma_f32_16x16x32_bf16(pf[m], vf, oacc[m][j], 0, 0, 0);
    }
    __builtin_amdgcn_s_setprio(0);

    // ---- pipelined staging with counted vmcnt (never 0 until drain) ----
    if (i < 15) {
      asm volatile("s_waitcnt lgkmcnt(0)" ::: "memory");
      __builtin_amdgcn_s_barrier();                  // all waves done reading
      if (i < 14) {
        STAGE_T(i + 2, g * 2 + (i & 1));
        asm volatile("s_waitcnt vmcnt(3)" ::: "memory");   // tile i+1 landed
      } else {
        asm volatile("s_waitcnt vmcnt(0)" ::: "memory");   // last tile landed
      }
      __builtin_amdgcn_s_barrier();
    }
  }
#undef STAGE_T

  // ---- cross-group combine: g1 -> LDS (f32), g0 adds + finishes ----
  __builtin_amdgcn_s_barrier();                    // all waves done with bufs
  float* Of = (float*)lds;                         // 128q x 64d f32 = 32 KB
  float* Rf = (float*)Pl;                          // 128q x 16 f32 = 8 KB
  if (g == 1) {
#pragma unroll
    for (int m = 0; m < 2; ++m) {
#pragma unroll
      for (int j = 0; j < 4; ++j)
#pragma unroll
        for (int r = 0; r < 4; ++r)
          Of[(wg * 32 + m * 16 + quad * 4 + r) * 64 + j * 16 + mrow] = oacc[m][j][r];
#pragma unroll
      for (int r = 0; r < 4; ++r)
        Rf[(wg * 32 + m * 16 + quad * 4 + r) * 16 + mrow] = rsl[m][r];
    }
  }
  __builtin_amdgcn_s_barrier();
  if (g == 0) {
#pragma unroll
    for (int m = 0; m < 2; ++m) {
#pragma unroll
      for (int j = 0; j < 4; ++j)
#pragma unroll
        for (int r = 0; r < 4; ++r)
          oacc[m][j][r] += Of[(wg * 32 + m * 16 + quad * 4 + r) * 64 + j * 16 + mrow];
#pragma unroll
      for (int r = 0; r < 4; ++r)
        rsl[m][r] += Rf[(wg * 32 + m * 16 + quad * 4 + r) * 16 + mrow];
    }
    // rowsum butterfly across 16 mrow lanes, normalize, write
#pragma unroll
    for (int m = 0; m < 2; ++m) {
#pragma unroll
      for (int d = 1; d < 16; d <<= 1) {
        f32x4 o;
#pragma unroll
        for (int r = 0; r < 4; ++r) o[r] = __shfl_xor(rsl[m][r], d, 64);
        rsl[m] += o;
      }
      f32x4 inv;
#pragma unroll
      for (int r = 0; r < 4; ++r) inv[r] = 1.0f / (rsl[m][r] + 1e-6f);
#pragma unroll
      for (int j = 0; j < 4; ++j) {
        int col = hoff + j * 16 + mrow;
#pragma unroll
        for (int r = 0; r < 4; ++r) {
          int t = qt * 128 + wg * 32 + m * 16 + quad * 4 + r;
          AO[(size_t)(t * 4 + b) * 1024 + col] = (__bf16)(oacc[m][j][r] * inv[r]);
        }
      }
    }
  }
}

extern "C" void kernel_launch(void* const* d_in, const int* in_sizes, int n_in,
                              void* d_out, int out_size, void* d_ws, size_t ws_size,
                              hipStream_t stream) {
  const float* query = (const float*)d_in[0];
  const float* key   = (const float*)d_in[1];
  const float* value = (const float*)d_in[2];
  const float* Wq    = (const float*)d_in[3];
  const float* Wk1   = (const float*)d_in[4];
  const float* Wk2   = (const float*)d_in[5];
  const float* Wv    = (const float*)d_in[6];
  const float* bin   = (const float*)d_in[7];
  const float* Wo    = (const float*)d_in[8];
  const float* bo    = (const float*)d_in[9];
  const float* pi    = (const float*)d_in[10];
  float* out = (float*)d_out;

  __bf16* qc  = (__bf16*)d_ws;          // 3*P4: qc|kc|vc
  __bf16* wq  = qc  + 3 * P4S;          // 5*P1: wq|wk1|wk2|wv|wo
  __bf16* wo  = wq  + 4 * P1S;
  __bf16* Qp  = wq  + 5 * P1S;          // 4*P4: Qp|K1p|K2p|Vp
  __bf16* K1p = Qp  + P4S;
  __bf16* K2p = K1p + P4S;
  __bf16* Vp  = K2p + P4S;
  __bf16* AO  = Vp  + P4S;
  float*  qn_g = (float*)(AO + P4S);    // 256 KB: [bh][1024]
  float*  knr  = qn_g + 64 * 1024;      // 512 KB: [bh][kt32][{k1:32,k2:32}]
  __bf16* Vt_g = qc;                    // reuse: qc dead after proj_gemm4

  cvt_all<<<8704, 256, 0, stream>>>(query, key, value, Wq, Wk1, Wk2, Wv, Wo, qc);

  // 4 projections + fused row-norms (qn / knr): 256 blocks = 1/CU
  proj_gemm4<<<dim3(M_DIM / 256, E_DIM / 256, 4), 512, 0, stream>>>(
      qc, wq, bin, Qp, qn_g, knr);

  // V transpose only
  vt_only<<<1024, 256, 0, stream>>>(Vp, Vt_g);

  // 512 blocks x 512 thr (2 key-groups x 4 waves), 72 KB -> 2 blocks/CU,
  // 16 waves/CU
  mgk_attn_mfma<<<512, 512, 0, stream>>>(
      Qp, K1p, K2p, Vt_g, qn_g, knr, pi, AO);

  out_gemm<<<dim3(M_DIM / 128, E_DIM / 128), 256, 0, stream>>>(AO, wo, bo, out);
}

// Round 9
// 238.795 us; speedup vs baseline: 1.0336x; 1.0336x over previous
//
#include <hip/hip_runtime.h>
#include <hip/hip_bf16.h>

#define T_DIM 1024
#define B_DIM 4
#define E_DIM 1024
#define H_DIM 16
#define HD    64
#define M_DIM (T_DIM * B_DIM)   // 4096

typedef __hip_bfloat16 bf16;
typedef __bf16 bf16x8 __attribute__((ext_vector_type(8)));
typedef __bf16 bf16x4 __attribute__((ext_vector_type(4)));
typedef __bf16 bf16x2 __attribute__((ext_vector_type(2)));
typedef float  f32x4  __attribute__((ext_vector_type(4)));

#define P4S ((size_t)M_DIM * E_DIM)   // 4194304
#define P1S ((size_t)E_DIM * E_DIM)   // 1048576

// ------------------------------------------- fused f32 -> bf16 (all 8 buffers)
__global__ __launch_bounds__(256) void cvt_all(
    const float* __restrict__ q, const float* __restrict__ k,
    const float* __restrict__ v, const float* __restrict__ w0,
    const float* __restrict__ w1, const float* __restrict__ w2,
    const float* __restrict__ w3, const float* __restrict__ w4,
    __bf16* __restrict__ dst)
{
  size_t i = ((size_t)blockIdx.x * 256 + threadIdx.x) * 8;
  const float* src;
  size_t off;
  if (i < P4S)            { src = q; off = i; }
  else if (i < 2 * P4S)   { src = k; off = i - P4S; }
  else if (i < 3 * P4S)   { src = v; off = i - 2 * P4S; }
  else {
    size_t j = i - 3 * P4S;
    int wsel = (int)(j >> 20);          // /P1S
    off = j & (P1S - 1);
    const float* ws[5] = {w0, w1, w2, w3, w4};
    src = ws[wsel];
  }
  float4 a = *(const float4*)(src + off);
  float4 b = *(const float4*)(src + off + 4);
  bf16x8 o;
  o[0] = (__bf16)a.x; o[1] = (__bf16)a.y; o[2] = (__bf16)a.z; o[3] = (__bf16)a.w;
  o[4] = (__bf16)b.x; o[5] = (__bf16)b.y; o[6] = (__bf16)b.z; o[7] = (__bf16)b.w;
  *(bf16x8*)(dst + i) = o;
}

// ------------------------------------------------- async global->LDS, 16 B/lane
__device__ __forceinline__ void load_lds16(const __bf16* g, __bf16* l) {
  __builtin_amdgcn_global_load_lds(
      (__attribute__((address_space(1))) void*)(void*)g,
      (__attribute__((address_space(3))) void*)l, 16, 0, 0);
}

// =======================================================================
// 256x256 8-phase GEMM (BK=64, 8 waves, dbuf LDS, counted vmcnt, swizzle)
// Plain epilogue (norm fusion REVERTED -- it cost ~10us in proj, r6->r8).
// =======================================================================
__device__ __forceinline__ void stage_half(
    int H, const __bf16* __restrict__ X, const __bf16* __restrict__ W,
    int bm, int bn, __bf16* As, __bf16* Bs, int tid)
{
  if (H >= 64) return;                 // K=1024 -> 16 tiles -> 64 half-tiles
  const int T  = H >> 2;
  const int h  = H & 3;
  const int rh = (h & 1) * 128;
  const __bf16* src = (h < 2) ? X : W;
  const int rbase   = (h < 2) ? bm : bn;
  __bf16* lb = ((h < 2) ? As : Bs) + (T & 1) * 16384;
#pragma unroll
  for (int li = 0; li < 2; ++li) {
    int r  = rh + li * 64 + (tid >> 3);          // row within 256-row tile
    int gc = (tid & 7) ^ (r & 7);                // pre-swizzled source chunk
    load_lds16(src + (size_t)(rbase + r) * E_DIM + T * 64 + gc * 8,
               lb + (rh + li * 64) * 64 + tid * 8);   // linear dest
  }
}

#define RD(base, row, c) \
  (*(const bf16x8*)((base) + (row) * 64 + ((((c) ^ ((row) & 7))) << 3)))

__global__ __launch_bounds__(512, 2) void proj_gemm4(
    const __bf16* __restrict__ xbase, const __bf16* __restrict__ wbase,
    const float* __restrict__ bin, __bf16* __restrict__ cbase)
{
  __shared__ __bf16 lds[65536];        // 128 KiB
  __bf16* As = lds;
  __bf16* Bs = lds + 32768;

  const int z = blockIdx.z;
  const __bf16* X = xbase + ((z == 0) ? 0 : (z == 3) ? 2 * P4S : P4S);
  const __bf16* W = wbase + (size_t)z * P1S;
  const float* bias = bin + z * E_DIM;
  __bf16* C = cbase + (size_t)z * P4S;

  const int bm = blockIdx.x * 256;
  const int bn = blockIdx.y * 256;

  const int tid  = threadIdx.x;
  const int lane = tid & 63;
  const int w    = tid >> 6;           // 8 waves
  const int wm   = w >> 2;
  const int wn   = w & 3;
  const int mrow = lane & 15, quad = lane >> 4;

  f32x4 acc[8][4];
#pragma unroll
  for (int m = 0; m < 8; ++m)
#pragma unroll
    for (int n = 0; n < 4; ++n) acc[m][n] = (f32x4)0.0f;

#pragma unroll
  for (int H = 0; H < 5; ++H) stage_half(H, X, W, bm, bn, As, Bs, tid);
  asm volatile("s_waitcnt vmcnt(2)" ::: "memory");
  __builtin_amdgcn_s_barrier();

  bf16x8 af[4][2];
  bf16x8 bq[4][2];

#pragma unroll 2
  for (int t = 0; t < 16; ++t) {
    const __bf16* Ab = As + (t & 1) * 16384;
    const __bf16* Bb = Bs + (t & 1) * 16384;

    // phase 0
#pragma unroll
    for (int n = 0; n < 2; ++n)
#pragma unroll
      for (int kk = 0; kk < 2; ++kk)
        bq[n][kk] = RD(Bb, wn * 64 + n * 16 + mrow, kk * 4 + quad);
#pragma unroll
    for (int m = 0; m < 4; ++m)
#pragma unroll
      for (int kk = 0; kk < 2; ++kk)
        af[m][kk] = RD(Ab, wm * 128 + m * 16 + mrow, kk * 4 + quad);
    stage_half(4 * t + 5, X, W, bm, bn, As, Bs, tid);
    __builtin_amdgcn_s_barrier();
    asm volatile("s_waitcnt lgkmcnt(0)" ::: "memory");
    __builtin_amdgcn_s_setprio(1);
#pragma unroll
    for (int kk = 0; kk < 2; ++kk)
#pragma unroll
      for (int n = 0; n < 2; ++n)
#pragma unroll
        for (int m = 0; m < 4; ++m)
          acc[m][n] = __builtin_amdgcn_mfma_f32_16x16x32_bf16(
              af[m][kk], bq[n][kk], acc[m][n], 0, 0, 0);
    __builtin_amdgcn_s_setprio(0);
    __builtin_amdgcn_s_barrier();

    // phase 1
#pragma unroll
    for (int n = 2; n < 4; ++n)
#pragma unroll
      for (int kk = 0; kk < 2; ++kk)
        bq[n][kk] = RD(Bb, wn * 64 + n * 16 + mrow, kk * 4 + quad);
    stage_half(4 * t + 6, X, W, bm, bn, As, Bs, tid);
    __builtin_amdgcn_s_barrier();
    asm volatile("s_waitcnt lgkmcnt(0)" ::: "memory");
    __builtin_amdgcn_s_setprio(1);
#pragma unroll
    for (int kk = 0; kk < 2; ++kk)
#pragma unroll
      for (int n = 2; n < 4; ++n)
#pragma unroll
        for (int m = 0; m < 4; ++m)
          acc[m][n] = __builtin_amdgcn_mfma_f32_16x16x32_bf16(
              af[m][kk], bq[n][kk], acc[m][n], 0, 0, 0);
    __builtin_amdgcn_s_setprio(0);
    __builtin_amdgcn_s_barrier();

    // phase 2
#pragma unroll
    for (int m = 0; m < 4; ++m)
#pragma unroll
      for (int kk = 0; kk < 2; ++kk)
        af[m][kk] = RD(Ab, wm * 128 + 64 + m * 16 + mrow, kk * 4 + quad);
    stage_half(4 * t + 7, X, W, bm, bn, As, Bs, tid);
    __builtin_amdgcn_s_barrier();
    asm volatile("s_waitcnt lgkmcnt(0)" ::: "memory");
    __builtin_amdgcn_s_setprio(1);
#pragma unroll
    for (int kk = 0; kk < 2; ++kk)
#pragma unroll
      for (int n = 0; n < 2; ++n)
#pragma unroll
        for (int m = 0; m < 4; ++m)
          acc[4 + m][n] = __builtin_amdgcn_mfma_f32_16x16x32_bf16(
              af[m][kk], bq[n][kk], acc[4 + m][n], 0, 0, 0);
    __builtin_amdgcn_s_setprio(0);
    __builtin_amdgcn_s_barrier();

    // phase 3
    stage_half(4 * t + 8, X, W, bm, bn, As, Bs, tid);
    __builtin_amdgcn_s_barrier();
    __builtin_amdgcn_s_setprio(1);
#pragma unroll
    for (int kk = 0; kk < 2; ++kk)
#pragma unroll
      for (int n = 2; n < 4; ++n)
#pragma unroll
        for (int m = 0; m < 4; ++m)
          acc[4 + m][n] = __builtin_amdgcn_mfma_f32_16x16x32_bf16(
              af[m][kk], bq[n][kk], acc[4 + m][n], 0, 0, 0);
    __builtin_amdgcn_s_setprio(0);
    if (t < 14)       { asm volatile("s_waitcnt vmcnt(2)" ::: "memory"); }
    else if (t == 14) { asm volatile("s_waitcnt vmcnt(0)" ::: "memory"); }
    __builtin_amdgcn_s_barrier();
  }

  // plain epilogue
#pragma unroll
  for (int n = 0; n < 4; ++n) {
    int col = bn + wn * 64 + n * 16 + mrow;
    float bc = bias[col];
#pragma unroll
    for (int m = 0; m < 8; ++m) {
      int rbase = bm + wm * 128 + m * 16 + quad * 4;
#pragma unroll
      for (int r = 0; r < 4; ++r)
        C[(size_t)(rbase + r) * E_DIM + col] = (__bf16)(acc[m][n][r] + bc);
    }
  }
}

// --------------------------------------------------- GEMM core (128x128, BK=32)
template <typename TO>
__device__ __forceinline__ void gemm_body(
    const __bf16* __restrict__ X, const __bf16* __restrict__ W,
    const float* __restrict__ bias, TO* __restrict__ C,
    int bm, int bn, int Ndim, int Kdim, __bf16* As, __bf16* Bs)
{
  const int tid  = threadIdx.x;
  const int lane = tid & 63;
  const int wave = tid >> 6;
  const int wy = (wave >> 1) * 64;
  const int wx = (wave & 1) * 64;
  const int mrow = lane & 15, quad = lane >> 4;

  const int srow = tid >> 2;
  const int ke   = (tid & 3) * 8;
  const __bf16* gA0 = X + (size_t)(bm + srow)      * Kdim + ke;
  const __bf16* gA1 = X + (size_t)(bm + srow + 64) * Kdim + ke;
  const __bf16* gB0 = W + (size_t)(bn + srow)      * Kdim + ke;
  const __bf16* gB1 = W + (size_t)(bn + srow + 64) * Kdim + ke;
  __bf16* lA0 = As + tid * 8;
  __bf16* lA1 = As + (tid + 256) * 8;
  __bf16* lB0 = Bs + tid * 8;
  __bf16* lB1 = Bs + (tid + 256) * 8;

  f32x4 acc[4][4];
#pragma unroll
  for (int i = 0; i < 4; ++i)
#pragma unroll
    for (int j = 0; j < 4; ++j) acc[i][j] = (f32x4)0.0f;

  for (int k0 = 0; k0 < Kdim; k0 += 32) {
    __syncthreads();
    load_lds16(gA0 + k0, lA0);
    load_lds16(gA1 + k0, lA1);
    load_lds16(gB0 + k0, lB0);
    load_lds16(gB1 + k0, lB1);
    __syncthreads();
    bf16x8 af[4], bf[4];
#pragma unroll
    for (int i = 0; i < 4; ++i)
      af[i] = *(const bf16x8*)(As + (wy + i * 16 + mrow) * 32 + quad * 8);
#pragma unroll
    for (int j = 0; j < 4; ++j)
      bf[j] = *(const bf16x8*)(Bs + (wx + j * 16 + mrow) * 32 + quad * 8);
#pragma unroll
    for (int i = 0; i < 4; ++i)
#pragma unroll
      for (int j = 0; j < 4; ++j)
        acc[i][j] = __builtin_amdgcn_mfma_f32_16x16x32_bf16(af[i], bf[j], acc[i][j], 0, 0, 0);
  }

#pragma unroll
  for (int j = 0; j < 4; ++j) {
    int col = bn + wx + j * 16 + mrow;
    float bc = bias[col];
#pragma unroll
    for (int i = 0; i < 4; ++i) {
      int rbase = bm + wy + i * 16 + quad * 4;
#pragma unroll
      for (int r = 0; r < 4; ++r)
        C[(size_t)(rbase + r) * Ndim + col] = (TO)(acc[i][j][r] + bc);
    }
  }
}

// Output projection (f32 out).
__global__ __launch_bounds__(256) void out_gemm(
    const __bf16* __restrict__ X, const __bf16* __restrict__ W,
    const float* __restrict__ bias, float* __restrict__ C)
{
  __shared__ __bf16 As[128 * 32];
  __shared__ __bf16 Bs[128 * 32];
  gemm_body<float>(X, W, bias, C, blockIdx.x * 128, blockIdx.y * 128,
                   E_DIM, E_DIM, As, Bs);
}

// ---------------- merged: norms (qn + knr sigma32 layout) + V transpose
// blocks [0,768): norms. blocks [768, 768+1024): V transpose (sigma32).
__global__ __launch_bounds__(256) void norms_vt(
    const __bf16* __restrict__ Qp, const __bf16* __restrict__ K1p,
    const __bf16* __restrict__ K2p, const __bf16* __restrict__ Vp,
    float* __restrict__ qn, float* __restrict__ knr,
    __bf16* __restrict__ Vt_g)
{
  __shared__ __bf16 tile[64][88];
  const int tid = threadIdx.x;
  if (blockIdx.x < 768) {
    int id = blockIdx.x * 256 + tid;           // 0..196607
    int which = id >> 16;
    int r = id & 65535;
    int bh = r >> 10, t = r & 1023;
    int b = bh >> 4, h = bh & 15;
    const __bf16* src = (which == 0) ? Qp : ((which == 1) ? K1p : K2p);
    const __bf16* p = src + (size_t)(t * 4 + b) * 1024 + h * 64;
    float s = 0.f;
#pragma unroll
    for (int c = 0; c < 8; ++c) {
      bf16x8 v = *(const bf16x8*)(p + c * 8);
#pragma unroll
      for (int j = 0; j < 8; ++j) { float x = (float)v[j]; s += x * x; }
    }
    if (which == 0)
      qn[bh * 1024 + t] = s;
    else
      knr[bh * 2048 + (t >> 5) * 64 + ((which == 2) ? 32 : 0)
          + (t & 15) * 2 + ((t >> 4) & 1)] = s;
    return;
  }
  // ---- V transpose: Vt_g[bh][d][kt32*32+s32(k)] = V[kt32*32+k][d],
  // s32(k) = (k&15)*2 + (k>>4)
  int bid = blockIdx.x - 768;
  const int bh = bid & 63, kt = bid >> 6;        // kt = 64-key tile
  const int b = bh >> 4, h = bh & 15;
  {
    int s = tid >> 2, d0 = (tid & 3) * 16;
    const __bf16* src = Vp + (size_t)((kt * 64 + s) * 4 + b) * 1024 + h * 64 + d0;
    *(bf16x8*)(&tile[s][d0])     = *(const bf16x8*)(src);
    *(bf16x8*)(&tile[s][d0 + 8]) = *(const bf16x8*)(src + 8);
  }
  __syncthreads();
#pragma unroll
  for (int c = 0; c < 2; ++c) {
    int idx = tid * 2 + c;
    int d = idx >> 3, u0 = (idx & 7) * 8;
    bf16x8 o;
#pragma unroll
    for (int i = 0; i < 8; ++i) {
      int u = u0 + i;
      int s = (u >> 5) * 32 + ((u & 31) >> 1) + (u & 1) * 16;  // sigma32^-1
      o[i] = tile[s][d];
    }
    *(bf16x8*)(Vt_g + ((size_t)bh * 64 + d) * 1024 + kt * 64 + u0) = o;
  }
}

// -------------------------------------------------------- MFMA flash attention
// r7 structure (best measured: 44.7us): 256 thr / 4 waves / 32 q-rows m-blocked,
// 40 KB LDS, KVBLK=32 x 32 tiles dbuf, counted vmcnt(3), zero global ops in
// loop, paired-row XOR layouts (0 conflicts). NEW: rowsum via ones-MFMA --
// B-fragment of constant 1s (no LDS read) makes every output column
// sum_k P[q][k]; replaces per-tile VALU rsl adds + the final butterfly,
// riding the ~20%-busy matrix pipe.
__global__ __launch_bounds__(256, 2) void mgk_attn_mfma(
    const __bf16* __restrict__ Qp, const __bf16* __restrict__ K1p,
    const __bf16* __restrict__ K2p, const __bf16* __restrict__ Vt_g,
    const float* __restrict__ qn_g, const float* __restrict__ knr_g,
    const float* __restrict__ pi, __bf16* __restrict__ AO)
{
  // 2 bufs x 6144 elems {K1 2048 | K2 2048 | Vt 2048} | Pl 4096 | kn 4096
  __shared__ __bf16 lds[20480];          // 40 KB
  __bf16* Pl  = lds + 12288;             // 4 waves x 16 rows x 64 elems
  float*  knl = (float*)(lds + 16384);   // 2048 f32: [kt32][{k1:32,k2:32}]

  const int bid = blockIdx.x;
  const int bh  = (bid & 7) * 8 + ((bid >> 3) & 7);   // XCD-local bh groups
  const int qt  = bid >> 6;                           // 0..7
  const int b = bh >> 4, h = bh & 15;
  const int tid = threadIdx.x, lane = tid & 63, w = tid >> 6;   // 4 waves
  const int mrow = lane & 15, quad = lane >> 4;

  const float cl1 = 0.0625f * 1.4426950408889634f;   // (scaling/2)*log2e
  const float cl2 = 0.1875f * 1.4426950408889634f;   // (3*scaling/2)*log2e
  const float L1 = 2.0f * cl1, L2 = 2.0f * cl2;
  const float p1 = fminf(fmaxf(fabsf(pi[h]), 1e-6f), 2.0f);
  const float p2 = fminf(fmaxf(fabsf(pi[H_DIM + h]), 1e-6f), 2.0f);
  const float lp1 = __log2f(p1), lp2 = __log2f(p2);
  const int hoff = h * 64;

  // Q fragments (loop-invariant), m = 2 row-blocks of 16
  bf16x8 af[2][2];
  f32x4 aq2[2];
#pragma unroll
  for (int m = 0; m < 2; ++m) {
    const __bf16* qp = Qp + (size_t)((qt * 128 + w * 32 + m * 16 + mrow) * 4 + b) * 1024
                       + hoff + quad * 8;
    af[m][0] = *(const bf16x8*)(qp);
    af[m][1] = *(const bf16x8*)(qp + 32);
    f32x4 qnv = *(const f32x4*)(qn_g + bh * 1024 + qt * 128 + w * 32 + m * 16 + quad * 4);
#pragma unroll
    for (int r = 0; r < 4; ++r) aq2[m][r] = fmaf(cl1 - cl2, qnv[r], lp2);
  }

  // ones B-fragment for rowsum MFMA (constant, no LDS)
  bf16x8 onesv;
#pragma unroll
  for (int i = 0; i < 8; ++i) onesv[i] = (__bf16)1.0f;

  // staging geometry: thread t stages one 16B chunk per region
  const int srow = tid >> 3;                       // 0..31
  const int pch  = tid & 7;                        // physical chunk (linear dest)
  const int gcK  = pch ^ (srow & 7);               // K: logical d-chunk
  const __bf16* gK1 = K1p + (size_t)(srow * 4 + b) * 1024 + hoff + gcK * 8;
  const __bf16* gK2 = K2p + (size_t)(srow * 4 + b) * 1024 + hoff + gcK * 8;
  const int vcl = pch ^ (srow & 7);                // Vt: logical chunk
  const int vd  = (vcl >> 2) * 32 + srow;          // logical d row
  const int vu0 = (vcl & 3) * 8;                   // u start
  const __bf16* gVt = Vt_g + ((size_t)bh * 64 + vd) * 1024 + vu0;

#define STAGE_T(kt_, bsel_) do {                                              \
    __bf16* bb_ = lds + (bsel_) * 6144;                                       \
    load_lds16(gK1 + (size_t)(kt_) * 131072, bb_ + tid * 8);                  \
    load_lds16(gK2 + (size_t)(kt_) * 131072, bb_ + 2048 + tid * 8);           \
    load_lds16(gVt + (kt_) * 32,             bb_ + 4096 + tid * 8);           \
  } while (0)

  // prologue: kn (2 loads) then tiles 0,1 (3 each)
  load_lds16((const __bf16*)(knr_g + bh * 2048 + tid * 4),
             (__bf16*)knl + tid * 8);
  load_lds16((const __bf16*)(knr_g + bh * 2048 + 1024 + tid * 4),
             (__bf16*)knl + 2048 + tid * 8);
  STAGE_T(0, 0);
  STAGE_T(1, 1);
  asm volatile("s_waitcnt vmcnt(3)" ::: "memory");   // kn + tile0 landed
  __builtin_amdgcn_s_barrier();

  f32x4 oacc[2][4];
#pragma unroll
  for (int m = 0; m < 2; ++m)
#pragma unroll
    for (int j = 0; j < 4; ++j) oacc[m][j] = (f32x4)0.0f;
  f32x4 osum[2] = {(f32x4)0.0f, (f32x4)0.0f};

  for (int i = 0; i < 32; ++i) {
    const __bf16* buf = lds + (i & 1) * 6144;
    const __bf16* K1s = buf;
    const __bf16* K2s = buf + 2048;
    const __bf16* Vts = buf + 4096;

    // per-tile key-norm constants from LDS
    float2 f1 = *(const float2*)(knl + i * 64 + mrow * 2);
    float2 f2 = *(const float2*)(knl + i * 64 + 32 + mrow * 2);
    float nb1[2], s2v[2];
    nb1[0] = fmaf(-cl1, f1.x, lp1); nb1[1] = fmaf(-cl1, f1.y, lp1);
    s2v[0] = -cl2 * f2.x;           s2v[1] = -cl2 * f2.y;

    // ---- S1, S2 via MFMA (each K-frag read feeds both m-blocks) ----
    f32x4 acc1[2][2], acc2[2][2];
#pragma unroll
    for (int m = 0; m < 2; ++m)
#pragma unroll
      for (int j = 0; j < 2; ++j) { acc1[m][j] = (f32x4)0.0f; acc2[m][j] = (f32x4)0.0f; }
    __builtin_amdgcn_s_setprio(1);
#pragma unroll
    for (int kk = 0; kk < 2; ++kk)
#pragma unroll
      for (int j = 0; j < 2; ++j) {
        int row = j * 16 + mrow;
        int off = row * 64 + (((kk * 4 + quad) ^ (row & 7)) << 3);
        bf16x8 b1f = *(const bf16x8*)(K1s + off);
        bf16x8 b2f = *(const bf16x8*)(K2s + off);
#pragma unroll
        for (int m = 0; m < 2; ++m) {
          acc1[m][j] = __builtin_amdgcn_mfma_f32_16x16x32_bf16(af[m][kk], b1f, acc1[m][j], 0, 0, 0);
          acc2[m][j] = __builtin_amdgcn_mfma_f32_16x16x32_bf16(af[m][kk], b2f, acc2[m][j], 0, 0, 0);
        }
      }
    __builtin_amdgcn_s_setprio(0);

    // ---- P' = exp2(L1*S1 + nb1[j]) + exp2(L2*S2 + s2v[j] + aq2[m][r]) ----
#pragma unroll
    for (int m = 0; m < 2; ++m) {
      f32x4 pj[2];
#pragma unroll
      for (int j = 0; j < 2; ++j) {
        f32x4 p;
#pragma unroll
        for (int r = 0; r < 4; ++r) {
          float e1 = __builtin_amdgcn_exp2f(fmaf(L1, acc1[m][j][r], nb1[j]));
          float e2 = __builtin_amdgcn_exp2f(fmaf(L2, acc2[m][j][r], s2v[j] + aq2[m][r]));
          p[r] = e1 + e2;
        }
        pj[j] = p;
      }
      // key j*16+mrow -> sigma32 slot u = mrow*2+j; paired-row swizzled write
#pragma unroll
      for (int r = 0; r < 4; ++r) {
        int row  = quad * 4 + r;                     // q & 15
        int phys = (m * 4 + (mrow >> 2)) ^ (row & 7);
        bf16x2 pk; pk[0] = (__bf16)pj[0][r]; pk[1] = (__bf16)pj[1][r];
        *(bf16x2*)(Pl + w * 1024 + row * 64 + phys * 8 + (mrow & 3) * 2) = pk;
      }
    }
    // Pl is wave-private; per-wave LDS ops are in-order -> no barrier.

    // ---- O += P * V; rowsum += P * ones (matrix pipe, no LDS read) ----
    bf16x8 pf[2];
#pragma unroll
    for (int m = 0; m < 2; ++m)
      pf[m] = *(const bf16x8*)(Pl + w * 1024 + mrow * 64
                               + (((m * 4 + quad) ^ (mrow & 7)) << 3));
    __builtin_amdgcn_s_setprio(1);
#pragma unroll
    for (int m = 0; m < 2; ++m)
      osum[m] = __builtin_amdgcn_mfma_f32_16x16x32_bf16(pf[m], onesv, osum[m], 0, 0, 0);
#pragma unroll
    for (int j = 0; j < 4; ++j) {
      int rowv = (j & 1) * 16 + mrow;                // d & 31
      int cl   = (j >> 1) * 4 + quad;
      bf16x8 vf = *(const bf16x8*)(Vts + rowv * 64 + ((cl ^ (rowv & 7)) << 3));
#pragma unroll
      for (int m = 0; m < 2; ++m)
        oacc[m][j] = __builtin_amdgcn_mfma_f32_16x16x32_bf16(pf[m], vf, oacc[m][j], 0, 0, 0);
    }
    __builtin_amdgcn_s_setprio(0);

    // ---- pipelined staging with counted vmcnt (never 0 until drain) ----
    if (i < 31) {
      asm volatile("s_waitcnt lgkmcnt(0)" ::: "memory");
      __builtin_amdgcn_s_barrier();                  // all waves done reading
      if (i < 30) {
        STAGE_T(i + 2, i & 1);
        asm volatile("s_waitcnt vmcnt(3)" ::: "memory");   // tile i+1 landed
      } else {
        asm volatile("s_waitcnt vmcnt(0)" ::: "memory");   // last tile landed
      }
      __builtin_amdgcn_s_barrier();
    }
  }
#undef STAGE_T

  // normalize + write (osum already holds the rowsum in every column)
#pragma unroll
  for (int m = 0; m < 2; ++m) {
    f32x4 inv;
#pragma unroll
    for (int r = 0; r < 4; ++r) inv[r] = 1.0f / (osum[m][r] + 1e-6f);
#pragma unroll
    for (int j = 0; j < 4; ++j) {
      int col = hoff + j * 16 + mrow;
#pragma unroll
      for (int r = 0; r < 4; ++r) {
        int t = qt * 128 + w * 32 + m * 16 + quad * 4 + r;
        AO[(size_t)(t * 4 + b) * 1024 + col] = (__bf16)(oacc[m][j][r] * inv[r]);
      }
    }
  }
}

extern "C" void kernel_launch(void* const* d_in, const int* in_sizes, int n_in,
                              void* d_out, int out_size, void* d_ws, size_t ws_size,
                              hipStream_t stream) {
  const float* query = (const float*)d_in[0];
  const float* key   = (const float*)d_in[1];
  const float* value = (const float*)d_in[2];
  const float* Wq    = (const float*)d_in[3];
  const float* Wk1   = (const float*)d_in[4];
  const float* Wk2   = (const float*)d_in[5];
  const float* Wv    = (const float*)d_in[6];
  const float* bin   = (const float*)d_in[7];
  const float* Wo    = (const float*)d_in[8];
  const float* bo    = (const float*)d_in[9];
  const float* pi    = (const float*)d_in[10];
  float* out = (float*)d_out;

  __bf16* qc  = (__bf16*)d_ws;          // 3*P4: qc|kc|vc
  __bf16* wq  = qc  + 3 * P4S;          // 5*P1: wq|wk1|wk2|wv|wo
  __bf16* wo  = wq  + 4 * P1S;
  __bf16* Qp  = wq  + 5 * P1S;          // 4*P4: Qp|K1p|K2p|Vp
  __bf16* K1p = Qp  + P4S;
  __bf16* K2p = K1p + P4S;
  __bf16* Vp  = K2p + P4S;
  __bf16* AO  = Vp  + P4S;
  float*  qn_g = (float*)(AO + P4S);    // 256 KB: [bh][1024]
  float*  knr  = qn_g + 64 * 1024;      // 512 KB: [bh][kt32][{k1:32,k2:32}]
  __bf16* Vt_g = qc;                    // reuse: qc dead after proj_gemm4

  cvt_all<<<8704, 256, 0, stream>>>(query, key, value, Wq, Wk1, Wk2, Wv, Wo, qc);

  // 4 projections, plain epilogue (norm fusion reverted)
  proj_gemm4<<<dim3(M_DIM / 256, E_DIM / 256, 4), 512, 0, stream>>>(qc, wq, bin, Qp);

  // merged norms (qn + knr) + sigma32 V transpose
  norms_vt<<<768 + 1024, 256, 0, stream>>>(Qp, K1p, K2p, Vp,
                                           qn_g, knr, Vt_g);

  // 512 blocks x 256 thr, 40 KB LDS (r7 structure + ones-MFMA rowsum)
  mgk_attn_mfma<<<512, 256, 0, stream>>>(
      Qp, K1p, K2p, Vt_g, qn_g, knr, pi, AO);

  out_gemm<<<dim3(M_DIM / 128, E_DIM / 128), 256, 0, stream>>>(AO, wo, bo, out);
}